// Round 8
// baseline (370.535 us; speedup 1.0000x reference)
//
#include <hip/hip_runtime.h>
#include <math.h>

#define TPB 512
#define LDM 72            // bf16 row stride (144 B): 16B-aligned b128, mild banks
#define SLOTS 4608        // 64*72 shorts = one 64x64 bf16 matrix slot

// ---------------------------------------------------------------------------
// N=129, B=128, D=64, NOUT=65, NIN=64, NMID=63
// x: (129,128,2) fp32 | mps_input mi2[n*4096+l*64+r]=(t0,t1) | mps_output
// mo4[n*4096+l*64+r]=(00,01,10,11).  out: 129 fp32 (128 per-b + lnrm).
//
// R8: bf16 16x16x32 MFMA (verified layout), column-ownership: MFMA waves
// w=0,1 own col strips [32w,32w+32); stage1 U=S*G writes own strip, stage2
// G^T*U re-reads only own strip (same-wave LDS dep, no barrier). S A-frags
// loaded once per congruence, reused across generators. Builder waves w=4-7
// transpose next generators global->LDS concurrently. lnrm 4 barriers/site,
// scan 3/step. Storage: Mstor[c*LDM+r] = M[r][c] (col-major); S symmetric.
// Slots: 0=S, 1-4=U0..U3 (4=Smid in scan), 5-6=Gi, 7-10=Go.
// ---------------------------------------------------------------------------

typedef __attribute__((ext_vector_type(8))) short bf16x8;
typedef __attribute__((ext_vector_type(4))) float f32x4;
typedef unsigned short US;

__device__ __forceinline__ US f2b(float f) {
    union { float f; unsigned u; } v; v.f = f;
    return (US)((v.u + 0x7FFFu + ((v.u >> 16) & 1u)) >> 16);
}
__device__ __forceinline__ float bf2f(US h) {
    union { unsigned u; float f; } v; v.u = ((unsigned)h) << 16; return v.f;
}

struct Frag { bf16x8 lo, hi; };

// A/B fragment for 16 storage-rows starting row0, K=64 split in 2 halves
__device__ __forceinline__ Frag ldf(const US* buf, int row0, int lane) {
    const US* p = buf + (row0 + (lane & 15)) * LDM + ((lane >> 4) << 3);
    Frag f; f.lo = *(const bf16x8*)p; f.hi = *(const bf16x8*)(p + 32); return f;
}
__device__ __forceinline__ f32x4 mm(const Frag& a, const Frag& b, f32x4 c) {
    c = __builtin_amdgcn_mfma_f32_16x16x32_bf16(a.lo, b.lo, c, 0, 0, 0);
    c = __builtin_amdgcn_mfma_f32_16x16x32_bf16(a.hi, b.hi, c, 0, 0, 0);
    return c;
}
// write 16x16 C-tile transposed-bf16 (C layout: col=lane&15, row=quad*4+reg)
__device__ __forceinline__ void stt(US* dst, f32x4 d, float s,
                                    int col0, int row0, int lane) {
    ushort4 wv;
    wv.x = f2b(d.x * s); wv.y = f2b(d.y * s);
    wv.z = f2b(d.z * s); wv.w = f2b(d.w * s);
    *(ushort4*)(dst + (col0 + (lane & 15)) * LDM + row0 + ((lane >> 4) << 2)) = wv;
}

// Congruence S' = sum_g G_g^T S G_g for one wave's 32-col strip C0.
// acc[rt][ct]: output rows rt*16, cols C0+ct*16.
template<int NG>
__device__ __forceinline__ void congr(US* sm, int sSlot, int gSlot, int uSlot,
                                      f32x4 acc[4][2], int C0, int lane) {
    const US* S = sm + sSlot * SLOTS;
    Frag aS[4];
#pragma unroll
    for (int rt = 0; rt < 4; ++rt) aS[rt] = ldf(S, rt * 16, lane);
    // stage1: U_g[:, strip] = S * G_g
#pragma unroll
    for (int g = 0; g < NG; ++g) {
        const US* G = sm + (gSlot + g) * SLOTS;
        US* U = sm + (uSlot + g) * SLOTS;
        Frag b0 = ldf(G, C0, lane), b1 = ldf(G, C0 + 16, lane);
#pragma unroll
        for (int rt = 0; rt < 4; ++rt) {
            f32x4 z0 = {0.f, 0.f, 0.f, 0.f}; z0 = mm(aS[rt], b0, z0);
            stt(U, z0, 1.f, C0, rt * 16, lane);
            f32x4 z1 = {0.f, 0.f, 0.f, 0.f}; z1 = mm(aS[rt], b1, z1);
            stt(U, z1, 1.f, C0 + 16, rt * 16, lane);
        }
    }
#pragma unroll
    for (int rt = 0; rt < 4; ++rt) {
        acc[rt][0] = (f32x4){0.f, 0.f, 0.f, 0.f};
        acc[rt][1] = (f32x4){0.f, 0.f, 0.f, 0.f};
    }
    // stage2: acc += G_g^T U_g  (reads own U strip: same-wave dependency)
#pragma unroll
    for (int g = 0; g < NG; ++g) {
        const US* G = sm + (gSlot + g) * SLOTS;
        const US* U = sm + (uSlot + g) * SLOTS;
        Frag u0 = ldf(U, C0, lane), u1 = ldf(U, C0 + 16, lane);
#pragma unroll
        for (int rt = 0; rt < 4; ++rt) {
            Frag ga = ldf(G, rt * 16, lane);
            acc[rt][0] = mm(ga, u0, acc[rt][0]);
            acc[rt][1] = mm(ga, u1, acc[rt][1]);
        }
    }
}

__device__ __forceinline__ float accmax(const f32x4 acc[4][2]) {
    float m = 0.f;
#pragma unroll
    for (int rt = 0; rt < 4; ++rt)
#pragma unroll
        for (int ct = 0; ct < 2; ++ct)
            m = fmaxf(m, fmaxf(fmaxf(fabsf(acc[rt][ct].x), fabsf(acc[rt][ct].y)),
                               fmaxf(fabsf(acc[rt][ct].z), fabsf(acc[rt][ct].w))));
#pragma unroll
    for (int off = 32; off; off >>= 1) m = fmaxf(m, __shfl_down(m, off, 64));
    return m;
}

__device__ __forceinline__ void stacc(US* Sb, const f32x4 acc[4][2], float s,
                                      int C0, int lane) {
#pragma unroll
    for (int rt = 0; rt < 4; ++rt) {
        stt(Sb, acc[rt][0], s, C0, rt * 16, lane);
        stt(Sb, acc[rt][1], s, C0 + 16, rt * 16, lane);
    }
}

__global__ __launch_bounds__(TPB)
void mps_proj_kernel(const float* __restrict__ x,
                     const float* __restrict__ mi,
                     const float* __restrict__ mo,
                     float* __restrict__ out) {
    __shared__ __align__(16) US smem[11 * SLOTS];
#define SL(i) (smem + (i) * SLOTS)
    __shared__ float fsA[256];
    __shared__ float fsr[8];
    __shared__ float fsv[128];

    const int tid  = threadIdx.x;
    const int lane = tid & 63;
    const int w    = tid >> 6;
    const int C0   = (w & 1) * 32;       // MFMA-wave col strip (w<2)

    const float2* mi2 = (const float2*)mi;
    const float4* mo4 = (const float4*)mo;

    float logsum = 0.f;

    if (blockIdx.x < 128) {
        // =================== per-batch MPS scan, b = blockIdx.x ==================
        const int b = blockIdx.x;
        const float xa = x[b * 2 + 0], xb = x[b * 2 + 1];
        if (tid < 64) {
            float4 v = mo4[tid];
            fsA[tid * 2 + 0] = xa * v.x + xb * v.z;
            fsA[tid * 2 + 1] = xa * v.y + xb * v.w;
        }
        __syncthreads();
        float vals[8]; float mloc = 0.f;
#pragma unroll
        for (int j = 0; j < 8; ++j) {
            int pos = tid + j * TPB; int u = pos >> 6, d = pos & 63;
            float s = fsA[u * 2] * fsA[d * 2] + fsA[u * 2 + 1] * fsA[d * 2 + 1];
            vals[j] = s; mloc = fmaxf(mloc, fabsf(s));
        }
#pragma unroll
        for (int off = 32; off; off >>= 1) mloc = fmaxf(mloc, __shfl_down(mloc, off, 64));
        if (lane == 0) fsr[w] = mloc;
        __syncthreads();
        float amax = fsr[0];
#pragma unroll
        for (int i = 1; i < 8; ++i) amax = fmaxf(amax, fsr[i]);
        logsum = logf(amax);
        {
            float inv = 1.f / amax;
#pragma unroll
            for (int j = 0; j < 8; ++j) {
                int pos = tid + j * TPB;
                SL(0)[(pos >> 6) * LDM + (pos & 63)] = f2b(vals[j] * inv);
            }
        }
        if (w >= 4) {   // build Gi0 = Ain(0): Gstor[r=lane][l=16j+t]
            const int j = w - 4;
            const float x1a = x[256 + b * 2 + 0], x1b = x[256 + b * 2 + 1];
            bf16x8 g0, g1;
#pragma unroll
            for (int t = 0; t < 8; ++t) {
                float2 m0 = mi2[(16 * j + t) * 64 + lane];
                float2 m1 = mi2[(16 * j + 8 + t) * 64 + lane];
                g0[t] = (short)f2b(x1a * m0.x + x1b * m0.y);
                g1[t] = (short)f2b(x1a * m1.x + x1b * m1.y);
            }
            *(bf16x8*)(SL(5) + lane * LDM + 16 * j) = g0;
            *(bf16x8*)(SL(5) + lane * LDM + 16 * j + 8) = g1;
        }
        __syncthreads();

        for (int k = 0; k < 63; ++k) {
            // Phase A: Smid = Ain^T S Ain (w0,w1) || build X0,X1(k+1) (w4-7)
            if (w < 2) {
                f32x4 accA[4][2];
                congr<1>(smem, 0, 5, 1, accA, C0, lane);
                stacc(SL(4), accA, 1.f, C0, lane);       // Smid unscaled (bf16 ok)
            } else if (w >= 4) {
                const int j = w - 4;
                const float x0a = x[(2 * k + 2) * 256 + b * 2 + 0];
                const float x0b = x[(2 * k + 2) * 256 + b * 2 + 1];
                const float4* so = mo4 + (k + 1) * 4096;
                bf16x8 a0, a1, c0, c1;
#pragma unroll
                for (int t = 0; t < 8; ++t) {
                    float4 m0 = so[(16 * j + t) * 64 + lane];
                    float4 m1 = so[(16 * j + 8 + t) * 64 + lane];
                    a0[t] = (short)f2b(x0a * m0.x + x0b * m0.z);
                    c0[t] = (short)f2b(x0a * m0.y + x0b * m0.w);
                    a1[t] = (short)f2b(x0a * m1.x + x0b * m1.z);
                    c1[t] = (short)f2b(x0a * m1.y + x0b * m1.w);
                }
                *(bf16x8*)(SL(7) + lane * LDM + 16 * j) = a0;
                *(bf16x8*)(SL(7) + lane * LDM + 16 * j + 8) = a1;
                *(bf16x8*)(SL(8) + lane * LDM + 16 * j) = c0;
                *(bf16x8*)(SL(8) + lane * LDM + 16 * j + 8) = c1;
            }
            __syncthreads();
            // Phase C: acc = sum_t X_t^T Smid X_t (w0,w1) || build Ain(k+1)
            f32x4 acc[4][2];
            if (w < 2) {
                congr<2>(smem, 4, 7, 1, acc, C0, lane);
                float m = accmax(acc);
                if (lane == 0) fsr[w] = m;
            } else if (w >= 4) {
                const int j = w - 4;
                const float x1a = x[(2 * k + 3) * 256 + b * 2 + 0];
                const float x1b = x[(2 * k + 3) * 256 + b * 2 + 1];
                const float2* si = mi2 + (k + 1) * 4096;
                bf16x8 g0, g1;
#pragma unroll
                for (int t = 0; t < 8; ++t) {
                    float2 m0 = si[(16 * j + t) * 64 + lane];
                    float2 m1 = si[(16 * j + 8 + t) * 64 + lane];
                    g0[t] = (short)f2b(x1a * m0.x + x1b * m0.y);
                    g1[t] = (short)f2b(x1a * m1.x + x1b * m1.y);
                }
                *(bf16x8*)(SL(5) + lane * LDM + 16 * j) = g0;
                *(bf16x8*)(SL(5) + lane * LDM + 16 * j + 8) = g1;
            }
            __syncthreads();
            // Phase D: amax, log, scaled store
            {
                float a = fmaxf(fsr[0], fsr[1]);
                logsum += logf(a);
                if (w < 2) stacc(SL(0), acc, 1.f / a, C0, lane);
            }
            __syncthreads();
        }

        // ---- last site: out[b] = logsum + log(sum_i v_i^T S v_i) ----
        {
            const float x0a = x[128 * 256 + b * 2 + 0];
            const float x0b = x[128 * 256 + b * 2 + 1];
            if (tid < 64) {
                float4 v = mo4[64 * 4096 + tid * 64];
                fsA[tid * 2 + 0] = x0a * v.x + x0b * v.z;
                fsA[tid * 2 + 1] = x0a * v.y + x0b * v.w;
            }
            __syncthreads();
            if (tid < 128) {        // v[l][i] = sum_r Ain63[l][r] w[r][i]
                int dd = tid >> 1, ii = tid & 1;
                float s = 0.f;
                for (int r = 0; r < 64; ++r)
                    s += bf2f(SL(5)[r * LDM + dd]) * fsA[r * 2 + ii];
                fsv[tid] = s;
            }
            __syncthreads();
            float part = 0.f;
#pragma unroll
            for (int j = 0; j < 8; ++j) {
                int pos = tid + j * TPB; int dd = pos >> 6, uu = pos & 63;
                part += bf2f(SL(0)[dd * LDM + uu]) *
                        (fsv[dd * 2] * fsv[uu * 2] + fsv[dd * 2 + 1] * fsv[uu * 2 + 1]);
            }
#pragma unroll
            for (int off = 32; off; off >>= 1) part += __shfl_down(part, off, 64);
            if (lane == 0) fsr[w] = part;
            __syncthreads();
            if (tid == 0) {
                float t = 0.f;
#pragma unroll
                for (int i = 0; i < 8; ++i) t += fsr[i];
                out[b] = logsum + logf(t);
            }
        }
    } else {
        // ============================ lnrm scalar chain ==========================
        if (tid < 64) {
            float4 v = mo4[tid];
            fsA[tid * 4 + 0] = v.x; fsA[tid * 4 + 1] = v.y;
            fsA[tid * 4 + 2] = v.z; fsA[tid * 4 + 3] = v.w;
        }
        __syncthreads();
        float vals[8]; float mloc = 0.f;
#pragma unroll
        for (int j = 0; j < 8; ++j) {
            int pos = tid + j * TPB; int kk = pos >> 6, ll = pos & 63;
            float s = fsA[kk*4+0]*fsA[ll*4+0] + fsA[kk*4+1]*fsA[ll*4+1] +
                      fsA[kk*4+2]*fsA[ll*4+2] + fsA[kk*4+3]*fsA[ll*4+3];
            vals[j] = s; mloc = fmaxf(mloc, fabsf(s));
        }
#pragma unroll
        for (int off = 32; off; off >>= 1) mloc = fmaxf(mloc, __shfl_down(mloc, off, 64));
        if (lane == 0) fsr[w] = mloc;
        __syncthreads();
        float amax = fsr[0];
#pragma unroll
        for (int i = 1; i < 8; ++i) amax = fmaxf(amax, fsr[i]);
        logsum = logf(amax);
        {
            float inv = 1.f / amax;
#pragma unroll
            for (int j = 0; j < 8; ++j) {
                int pos = tid + j * TPB;
                SL(0)[(pos >> 6) * LDM + (pos & 63)] = f2b(vals[j] * inv);
            }
        }
        if (w >= 4) {   // build Gi0,Gi1 from mi[0]
            const int j = w - 4;
            bf16x8 g00, g01, g10, g11;
#pragma unroll
            for (int t = 0; t < 8; ++t) {
                float2 m0 = mi2[(16 * j + t) * 64 + lane];
                float2 m1 = mi2[(16 * j + 8 + t) * 64 + lane];
                g00[t] = (short)f2b(m0.x); g10[t] = (short)f2b(m0.y);
                g01[t] = (short)f2b(m1.x); g11[t] = (short)f2b(m1.y);
            }
            *(bf16x8*)(SL(5) + lane * LDM + 16 * j) = g00;
            *(bf16x8*)(SL(5) + lane * LDM + 16 * j + 8) = g01;
            *(bf16x8*)(SL(6) + lane * LDM + 16 * j) = g10;
            *(bf16x8*)(SL(6) + lane * LDM + 16 * j + 8) = g11;
        }
        __syncthreads();

        for (int n = 0; n < 64; ++n) {
            f32x4 acc[4][2];
            // Phase A: in-congruence (w0,w1) || build Go0..3 from mo[n+1]
            if (w < 2) {
                congr<2>(smem, 0, 5, 1, acc, C0, lane);
                float m = accmax(acc);
                if (lane == 0) fsr[w] = m;
            } else if (w >= 4) {
                const int j = w - 4;
                const float4* so = mo4 + (n + 1) * 4096;
                bf16x8 g[4][2];
#pragma unroll
                for (int t = 0; t < 8; ++t) {
                    float4 m0 = so[(16 * j + t) * 64 + lane];
                    float4 m1 = so[(16 * j + 8 + t) * 64 + lane];
                    g[0][0][t] = (short)f2b(m0.x); g[1][0][t] = (short)f2b(m0.y);
                    g[2][0][t] = (short)f2b(m0.z); g[3][0][t] = (short)f2b(m0.w);
                    g[0][1][t] = (short)f2b(m1.x); g[1][1][t] = (short)f2b(m1.y);
                    g[2][1][t] = (short)f2b(m1.z); g[3][1][t] = (short)f2b(m1.w);
                }
#pragma unroll
                for (int c = 0; c < 4; ++c) {
                    *(bf16x8*)(SL(7 + c) + lane * LDM + 16 * j) = g[c][0];
                    *(bf16x8*)(SL(7 + c) + lane * LDM + 16 * j + 8) = g[c][1];
                }
            }
            __syncthreads();
            // Phase B: a1, scaled store
            {
                float a1 = fmaxf(fsr[0], fsr[1]);
                logsum += logf(a1);
                if (w < 2) stacc(SL(0), acc, 1.f / a1, C0, lane);
            }
            __syncthreads();
            // Phase C: out-congruence (w0,w1) || build Gi(n+1)
            if (w < 2) {
                congr<4>(smem, 0, 7, 1, acc, C0, lane);
                float m = accmax(acc);
                if (lane == 0) fsr[w] = m;
            } else if (w >= 4 && n < 63) {
                const int j = w - 4;
                const float2* si = mi2 + (n + 1) * 4096;
                bf16x8 g00, g01, g10, g11;
#pragma unroll
                for (int t = 0; t < 8; ++t) {
                    float2 m0 = si[(16 * j + t) * 64 + lane];
                    float2 m1 = si[(16 * j + 8 + t) * 64 + lane];
                    g00[t] = (short)f2b(m0.x); g10[t] = (short)f2b(m0.y);
                    g01[t] = (short)f2b(m1.x); g11[t] = (short)f2b(m1.y);
                }
                *(bf16x8*)(SL(5) + lane * LDM + 16 * j) = g00;
                *(bf16x8*)(SL(5) + lane * LDM + 16 * j + 8) = g01;
                *(bf16x8*)(SL(6) + lane * LDM + 16 * j) = g10;
                *(bf16x8*)(SL(6) + lane * LDM + 16 * j + 8) = g11;
            }
            __syncthreads();
            // Phase D: a2, scaled store (or final output)
            {
                float a2 = fmaxf(fsr[0], fsr[1]);
                if (n < 63) {
                    logsum += logf(a2);
                    if (w < 2) stacc(SL(0), acc, 1.f / a2, C0, lane);
                } else {
                    // S[0][0]: wave0 strip, rt=0 ct=0, lane0 reg0
                    if (tid == 0) out[128] = logsum + logf(acc[0][0].x);
                }
            }
            __syncthreads();
        }
    }
#undef SL
}

extern "C" void kernel_launch(void* const* d_in, const int* in_sizes, int n_in,
                              void* d_out, int out_size, void* d_ws, size_t ws_size,
                              hipStream_t stream) {
    (void)in_sizes; (void)n_in; (void)d_ws; (void)ws_size; (void)out_size;
    const float* x  = (const float*)d_in[0];
    const float* mi = (const float*)d_in[1];
    const float* mo = (const float*)d_in[2];
    float* out = (float*)d_out;
    hipLaunchKernelGGL(mps_proj_kernel, dim3(129), dim3(TPB), 0, stream,
                       x, mi, mo, out);
}

// Round 9
// 262.604 us; speedup vs baseline: 1.4110x; 1.4110x over previous
//
#include <hip/hip_runtime.h>
#include <math.h>

#define TPB 512
#define LDM 72            // bf16 row stride (144 B): 16B-aligned b128
#define SLOTS 4608        // 64*72 shorts = one 64x64 bf16 matrix slot

// ---------------------------------------------------------------------------
// N=129, B=128, D=64, NOUT=65, NIN=64, NMID=63
// x: (129,128,2) fp32 | mps_input mi2[n*4096+l*64+r]=(t0,t1) | mps_output
// mo4[n*4096+l*64+r]=(00,01,10,11).  out: 129 fp32 (128 per-b + lnrm).
//
// R9: one phase per congruence. Wave ct (w<4) owns 16-col strip: stage1
// U=S*G (own strip) -> stage2 acc += G^T U, ALL generators summed in-register.
// Slots alternate (read 0 -> write 1 -> read 1 -> write 0): no store/read race.
// amax normalization DEFERRED one phase: divide by prev result's amax (from
// parity-buffered fsr), log added for every divisor -> exact telescoping.
// Waves 4-7 build next generators concurrently. lnrm: 2 barriers/site,
// scan: 2 barriers/step (was 4 / 3 in R8).
// Slots: 0=S, 1=S', 2-3=Gi, 4-7=Go, 8-11=U scratch (one per congr wave).
// ---------------------------------------------------------------------------

typedef __attribute__((ext_vector_type(8))) short bf16x8;
typedef __attribute__((ext_vector_type(4))) float f32x4;
typedef unsigned short US;

__device__ __forceinline__ US f2b(float f) {
    union { float f; unsigned u; } v; v.f = f;
    return (US)((v.u + 0x7FFFu + ((v.u >> 16) & 1u)) >> 16);
}
__device__ __forceinline__ float bf2f(US h) {
    union { unsigned u; float f; } v; v.u = ((unsigned)h) << 16; return v.f;
}

struct Frag { bf16x8 lo, hi; };

// fragment for 16 storage-rows starting row0, K=64 in 2 halves
__device__ __forceinline__ Frag ldf(const US* buf, int row0, int lane) {
    const US* p = buf + (row0 + (lane & 15)) * LDM + ((lane >> 4) << 3);
    Frag f; f.lo = *(const bf16x8*)p; f.hi = *(const bf16x8*)(p + 32); return f;
}
__device__ __forceinline__ f32x4 mm(const Frag& a, const Frag& b, f32x4 c) {
    c = __builtin_amdgcn_mfma_f32_16x16x32_bf16(a.lo, b.lo, c, 0, 0, 0);
    c = __builtin_amdgcn_mfma_f32_16x16x32_bf16(a.hi, b.hi, c, 0, 0, 0);
    return c;
}
// write 16x16 C-tile transposed-bf16 (C layout: col=lane&15, row=quad*4+reg)
__device__ __forceinline__ void stt(US* dst, f32x4 d, float s,
                                    int col0, int row0, int lane) {
    ushort4 wv;
    wv.x = f2b(d.x * s); wv.y = f2b(d.y * s);
    wv.z = f2b(d.z * s); wv.w = f2b(d.w * s);
    *(ushort4*)(dst + (col0 + (lane & 15)) * LDM + row0 + ((lane >> 4) << 2)) = wv;
}

// Full congruence for one 16-col strip C0: acc = sum_g G_g^T S G_g (in-reg sum)
template<int NG>
__device__ __forceinline__ void congr16(US* sm, int sSlot, int gSlot, US* Uw,
                                        f32x4 acc[4], int C0, int lane) {
    const US* S = sm + sSlot * SLOTS;
    Frag aS[4];
#pragma unroll
    for (int rt = 0; rt < 4; ++rt) aS[rt] = ldf(S, rt * 16, lane);
#pragma unroll
    for (int g = 0; g < NG; ++g) {           // stage1: U_g strip = S * G_g
        const US* G = sm + (gSlot + g) * SLOTS;
        US* Ug = Uw + g * (16 * LDM);
        Frag b = ldf(G, C0, lane);
#pragma unroll
        for (int rt = 0; rt < 4; ++rt) {
            f32x4 z = {0.f, 0.f, 0.f, 0.f};
            z = mm(aS[rt], b, z);
            stt(Ug, z, 1.f, 0, rt * 16, lane);
        }
    }
#pragma unroll
    for (int rt = 0; rt < 4; ++rt) acc[rt] = (f32x4){0.f, 0.f, 0.f, 0.f};
#pragma unroll
    for (int g = 0; g < NG; ++g) {           // stage2: acc += G_g^T U_g
        const US* G = sm + (gSlot + g) * SLOTS;
        const US* Ug = Uw + g * (16 * LDM);
        Frag u = ldf(Ug, 0, lane);
#pragma unroll
        for (int rt = 0; rt < 4; ++rt) {
            Frag ga = ldf(G, rt * 16, lane);
            acc[rt] = mm(ga, u, acc[rt]);
        }
    }
}

__device__ __forceinline__ void stacc16(US* Sb, const f32x4 acc[4], float s,
                                        int C0, int lane) {
#pragma unroll
    for (int rt = 0; rt < 4; ++rt) stt(Sb, acc[rt], s, C0, rt * 16, lane);
}

// scaled store + wave-max of stored values
__device__ __forceinline__ float stmax16(US* Sb, const f32x4 acc[4], float s,
                                         int C0, int lane) {
    float m = 0.f;
#pragma unroll
    for (int rt = 0; rt < 4; ++rt) {
        float vx = acc[rt].x * s, vy = acc[rt].y * s;
        float vz = acc[rt].z * s, vw = acc[rt].w * s;
        m = fmaxf(m, fmaxf(fmaxf(fabsf(vx), fabsf(vy)),
                           fmaxf(fabsf(vz), fabsf(vw))));
        ushort4 wv; wv.x = f2b(vx); wv.y = f2b(vy); wv.z = f2b(vz); wv.w = f2b(vw);
        *(ushort4*)(Sb + (C0 + (lane & 15)) * LDM + rt * 16 + ((lane >> 4) << 2)) = wv;
    }
#pragma unroll
    for (int off = 32; off; off >>= 1) m = fmaxf(m, __shfl_down(m, off, 64));
    return m;
}

__global__ __launch_bounds__(TPB)
void mps_proj_kernel(const float* __restrict__ x,
                     const float* __restrict__ mi,
                     const float* __restrict__ mo,
                     float* __restrict__ out) {
    __shared__ __align__(16) US smem[12 * SLOTS];
#define SL(i) (smem + (i) * SLOTS)
    __shared__ float fsA[256];
    __shared__ float fsp[8];
    __shared__ float fsrA[2][4];
    __shared__ float fsrB[2][4];
    __shared__ float fsv[128];

    const int tid  = threadIdx.x;
    const int lane = tid & 63;
    const int w    = tid >> 6;
    const int C0   = (w & 3) * 16;                 // congr strip (w<4)
    US* const Uw   = smem + (8 + (w & 3)) * SLOTS; // per-congr-wave U scratch

    const float2* mi2 = (const float2*)mi;
    const float4* mo4 = (const float4*)mo;

    float logsum = 0.f;
    f32x4 acc[4];

    if (blockIdx.x < 128) {
        // =================== per-batch MPS scan, b = blockIdx.x ==================
        const int b = blockIdx.x;
        const float xa = x[b * 2 + 0], xb = x[b * 2 + 1];
        if (tid < 64) {
            float4 v = mo4[tid];
            fsA[tid * 2 + 0] = xa * v.x + xb * v.z;
            fsA[tid * 2 + 1] = xa * v.y + xb * v.w;
        }
        __syncthreads();
        float vals[8]; float mloc = 0.f;
#pragma unroll
        for (int j = 0; j < 8; ++j) {
            int pos = tid + j * TPB; int u = pos >> 6, d = pos & 63;
            float s = fsA[u * 2] * fsA[d * 2] + fsA[u * 2 + 1] * fsA[d * 2 + 1];
            vals[j] = s; mloc = fmaxf(mloc, fabsf(s));
        }
#pragma unroll
        for (int off = 32; off; off >>= 1) mloc = fmaxf(mloc, __shfl_down(mloc, off, 64));
        if (lane == 0) fsp[w] = mloc;
        __syncthreads();
        float amax = fsp[0];
#pragma unroll
        for (int i = 1; i < 8; ++i) amax = fmaxf(amax, fsp[i]);
        logsum = logf(amax);
        {
            float inv = 1.f / amax;
#pragma unroll
            for (int j = 0; j < 8; ++j) {
                int pos = tid + j * TPB;
                SL(0)[(pos >> 6) * LDM + (pos & 63)] = f2b(vals[j] * inv);
            }
        }
        if (w >= 4) {   // build Gi = Ain(0) into slot 2
            const int j = w - 4;
            const float x1a = x[256 + b * 2 + 0], x1b = x[256 + b * 2 + 1];
            bf16x8 g0, g1;
#pragma unroll
            for (int t = 0; t < 8; ++t) {
                float2 m0 = mi2[(16 * j + t) * 64 + lane];
                float2 m1 = mi2[(16 * j + 8 + t) * 64 + lane];
                g0[t] = (short)f2b(x1a * m0.x + x1b * m0.y);
                g1[t] = (short)f2b(x1a * m1.x + x1b * m1.y);
            }
            *(bf16x8*)(SL(2) + lane * LDM + 16 * j) = g0;
            *(bf16x8*)(SL(2) + lane * LDM + 16 * j + 8) = g1;
        }
        if (tid < 4) fsrB[1][tid] = 1.f;   // deferred-scale init (S normalized)
        __syncthreads();

        for (int k = 0; k < 63; ++k) {
            // Phase A: Smid(slot1) = Ain^T S Ain, UNSCALED || build X0,X1(k+1)
            if (w < 4) {
                congr16<1>(smem, 0, 2, Uw, acc, C0, lane);
                stacc16(SL(1), acc, 1.f, C0, lane);
            } else {
                const int j = w - 4;
                const float x0a = x[(2 * k + 2) * 256 + b * 2 + 0];
                const float x0b = x[(2 * k + 2) * 256 + b * 2 + 1];
                const float4* so = mo4 + (k + 1) * 4096;
                bf16x8 a0, a1, c0, c1;
#pragma unroll
                for (int t = 0; t < 8; ++t) {
                    float4 m0 = so[(16 * j + t) * 64 + lane];
                    float4 m1 = so[(16 * j + 8 + t) * 64 + lane];
                    a0[t] = (short)f2b(x0a * m0.x + x0b * m0.z);
                    c0[t] = (short)f2b(x0a * m0.y + x0b * m0.w);
                    a1[t] = (short)f2b(x0a * m1.x + x0b * m1.z);
                    c1[t] = (short)f2b(x0a * m1.y + x0b * m1.w);
                }
                *(bf16x8*)(SL(4) + lane * LDM + 16 * j) = a0;
                *(bf16x8*)(SL(4) + lane * LDM + 16 * j + 8) = a1;
                *(bf16x8*)(SL(5) + lane * LDM + 16 * j) = c0;
                *(bf16x8*)(SL(5) + lane * LDM + 16 * j + 8) = c1;
            }
            __syncthreads();
            // Phase B: S(slot0) = (sum_t X_t^T Smid X_t)/a_prev || build Ain(k+1)
            if (w < 4) {
                float a = fmaxf(fmaxf(fsrB[(k + 1) & 1][0], fsrB[(k + 1) & 1][1]),
                                fmaxf(fsrB[(k + 1) & 1][2], fsrB[(k + 1) & 1][3]));
                logsum += logf(a);
                congr16<2>(smem, 1, 4, Uw, acc, C0, lane);
                float m = stmax16(SL(0), acc, 1.f / a, C0, lane);
                if (lane == 0) fsrB[k & 1][w] = m;
            } else {
                const int j = w - 4;
                const float x1a = x[(2 * k + 3) * 256 + b * 2 + 0];
                const float x1b = x[(2 * k + 3) * 256 + b * 2 + 1];
                const float2* si = mi2 + (k + 1) * 4096;
                bf16x8 g0, g1;
#pragma unroll
                for (int t = 0; t < 8; ++t) {
                    float2 m0 = si[(16 * j + t) * 64 + lane];
                    float2 m1 = si[(16 * j + 8 + t) * 64 + lane];
                    g0[t] = (short)f2b(x1a * m0.x + x1b * m0.y);
                    g1[t] = (short)f2b(x1a * m1.x + x1b * m1.y);
                }
                *(bf16x8*)(SL(2) + lane * LDM + 16 * j) = g0;
                *(bf16x8*)(SL(2) + lane * LDM + 16 * j + 8) = g1;
            }
            __syncthreads();
        }

        // ---- last site: out[b] = logsum + log(sum_i v_i^T S v_i) ----
        {
            const float x0a = x[128 * 256 + b * 2 + 0];
            const float x0b = x[128 * 256 + b * 2 + 1];
            if (tid < 64) {
                float4 v = mo4[64 * 4096 + tid * 64];
                fsA[tid * 2 + 0] = x0a * v.x + x0b * v.z;
                fsA[tid * 2 + 1] = x0a * v.y + x0b * v.w;
            }
            __syncthreads();
            if (tid < 128) {        // v[l][i] = sum_r Ain63[l][r] w[r][i]
                int dd = tid >> 1, ii = tid & 1;
                float s = 0.f;
                for (int r = 0; r < 64; ++r)
                    s += bf2f(SL(2)[r * LDM + dd]) * fsA[r * 2 + ii];
                fsv[tid] = s;
            }
            __syncthreads();
            float part = 0.f;
#pragma unroll
            for (int j = 0; j < 8; ++j) {
                int pos = tid + j * TPB; int dd = pos >> 6, uu = pos & 63;
                part += bf2f(SL(0)[dd * LDM + uu]) *
                        (fsv[dd * 2] * fsv[uu * 2] + fsv[dd * 2 + 1] * fsv[uu * 2 + 1]);
            }
#pragma unroll
            for (int off = 32; off; off >>= 1) part += __shfl_down(part, off, 64);
            if (lane == 0) fsp[w] = part;
            __syncthreads();
            if (tid == 0) {
                float t = 0.f;
#pragma unroll
                for (int i = 0; i < 8; ++i) t += fsp[i];
                out[b] = logsum + logf(t);
            }
        }
    } else {
        // ============================ lnrm scalar chain ==========================
        if (tid < 64) {
            float4 v = mo4[tid];
            fsA[tid * 4 + 0] = v.x; fsA[tid * 4 + 1] = v.y;
            fsA[tid * 4 + 2] = v.z; fsA[tid * 4 + 3] = v.w;
        }
        __syncthreads();
        float vals[8]; float mloc = 0.f;
#pragma unroll
        for (int j = 0; j < 8; ++j) {
            int pos = tid + j * TPB; int kk = pos >> 6, ll = pos & 63;
            float s = fsA[kk*4+0]*fsA[ll*4+0] + fsA[kk*4+1]*fsA[ll*4+1] +
                      fsA[kk*4+2]*fsA[ll*4+2] + fsA[kk*4+3]*fsA[ll*4+3];
            vals[j] = s; mloc = fmaxf(mloc, fabsf(s));
        }
#pragma unroll
        for (int off = 32; off; off >>= 1) mloc = fmaxf(mloc, __shfl_down(mloc, off, 64));
        if (lane == 0) fsp[w] = mloc;
        __syncthreads();
        float amax = fsp[0];
#pragma unroll
        for (int i = 1; i < 8; ++i) amax = fmaxf(amax, fsp[i]);
        logsum = logf(amax);
        {
            float inv = 1.f / amax;
#pragma unroll
            for (int j = 0; j < 8; ++j) {
                int pos = tid + j * TPB;
                SL(0)[(pos >> 6) * LDM + (pos & 63)] = f2b(vals[j] * inv);
            }
        }
        if (w >= 4) {   // build Gi0,Gi1 from mi[0] -> slots 2,3
            const int j = w - 4;
            bf16x8 g00, g01, g10, g11;
#pragma unroll
            for (int t = 0; t < 8; ++t) {
                float2 m0 = mi2[(16 * j + t) * 64 + lane];
                float2 m1 = mi2[(16 * j + 8 + t) * 64 + lane];
                g00[t] = (short)f2b(m0.x); g10[t] = (short)f2b(m0.y);
                g01[t] = (short)f2b(m1.x); g11[t] = (short)f2b(m1.y);
            }
            *(bf16x8*)(SL(2) + lane * LDM + 16 * j) = g00;
            *(bf16x8*)(SL(2) + lane * LDM + 16 * j + 8) = g01;
            *(bf16x8*)(SL(3) + lane * LDM + 16 * j) = g10;
            *(bf16x8*)(SL(3) + lane * LDM + 16 * j + 8) = g11;
        }
        if (tid < 4) fsrB[1][tid] = 1.f;
        __syncthreads();

        for (int n = 0; n < 64; ++n) {
            // Phase A: S'(slot1) = (sum_t Mi_t^T S Mi_t)/aB || build Go from mo[n+1]
            if (w < 4) {
                float aB = fmaxf(fmaxf(fsrB[(n + 1) & 1][0], fsrB[(n + 1) & 1][1]),
                                 fmaxf(fsrB[(n + 1) & 1][2], fsrB[(n + 1) & 1][3]));
                logsum += logf(aB);
                congr16<2>(smem, 0, 2, Uw, acc, C0, lane);
                float m = stmax16(SL(1), acc, 1.f / aB, C0, lane);
                if (lane == 0) fsrA[n & 1][w] = m;
            } else {
                const int j = w - 4;
                const float4* so = mo4 + (n + 1) * 4096;
                bf16x8 g[4][2];
#pragma unroll
                for (int t = 0; t < 8; ++t) {
                    float4 m0 = so[(16 * j + t) * 64 + lane];
                    float4 m1 = so[(16 * j + 8 + t) * 64 + lane];
                    g[0][0][t] = (short)f2b(m0.x); g[1][0][t] = (short)f2b(m0.y);
                    g[2][0][t] = (short)f2b(m0.z); g[3][0][t] = (short)f2b(m0.w);
                    g[0][1][t] = (short)f2b(m1.x); g[1][1][t] = (short)f2b(m1.y);
                    g[2][1][t] = (short)f2b(m1.z); g[3][1][t] = (short)f2b(m1.w);
                }
#pragma unroll
                for (int c = 0; c < 4; ++c) {
                    *(bf16x8*)(SL(4 + c) + lane * LDM + 16 * j) = g[c][0];
                    *(bf16x8*)(SL(4 + c) + lane * LDM + 16 * j + 8) = g[c][1];
                }
            }
            __syncthreads();
            // Phase B: S(slot0) = (sum_c Mo_c^T S' Mo_c)/aA || build Gi(n+1)
            if (w < 4) {
                float aA = fmaxf(fmaxf(fsrA[n & 1][0], fsrA[n & 1][1]),
                                 fmaxf(fsrA[n & 1][2], fsrA[n & 1][3]));
                logsum += logf(aA);
                congr16<4>(smem, 1, 4, Uw, acc, C0, lane);
                float m = stmax16(SL(0), acc, 1.f / aA, C0, lane);
                if (lane == 0) fsrB[n & 1][w] = m;
            } else if (n < 63) {
                const int j = w - 4;
                const float2* si = mi2 + (n + 1) * 4096;
                bf16x8 g00, g01, g10, g11;
#pragma unroll
                for (int t = 0; t < 8; ++t) {
                    float2 m0 = si[(16 * j + t) * 64 + lane];
                    float2 m1 = si[(16 * j + 8 + t) * 64 + lane];
                    g00[t] = (short)f2b(m0.x); g10[t] = (short)f2b(m0.y);
                    g01[t] = (short)f2b(m1.x); g11[t] = (short)f2b(m1.y);
                }
                *(bf16x8*)(SL(2) + lane * LDM + 16 * j) = g00;
                *(bf16x8*)(SL(2) + lane * LDM + 16 * j + 8) = g01;
                *(bf16x8*)(SL(3) + lane * LDM + 16 * j) = g10;
                *(bf16x8*)(SL(3) + lane * LDM + 16 * j + 8) = g11;
            }
            __syncthreads();
        }
        if (tid == 0) out[128] = logsum + logf(bf2f(SL(0)[0]));
    }
#undef SL
}

extern "C" void kernel_launch(void* const* d_in, const int* in_sizes, int n_in,
                              void* d_out, int out_size, void* d_ws, size_t ws_size,
                              hipStream_t stream) {
    (void)in_sizes; (void)n_in; (void)d_ws; (void)ws_size; (void)out_size;
    const float* x  = (const float*)d_in[0];
    const float* mi = (const float*)d_in[1];
    const float* mo = (const float*)d_in[2];
    float* out = (float*)d_out;
    hipLaunchKernelGGL(mps_proj_kernel, dim3(129), dim3(TPB), 0, stream,
                       x, mi, mo, out);
}